// Round 4
// baseline (252.568 us; speedup 1.0000x reference)
//
#include <hip/hip_runtime.h>
#include <stdint.h>

#define D 128
#define K_NEI 10
#define TILE_M 64   // fused-fallback tile

typedef __bf16 bf16x8 __attribute__((ext_vector_type(8)));
typedef float f32x4 __attribute__((ext_vector_type(4)));

__device__ __forceinline__ uint32_t f2bf(float f) {
    union { float f; uint32_t u; } v; v.f = f;
    uint32_t u = v.u;
    return (u + 0x7FFFu + ((u >> 16) & 1u)) >> 16;   // RNE
}
__device__ __forceinline__ float bf2f(uint32_t h) {
    union { uint32_t u; float f; } v; v.u = h << 16; return v.f;
}
__device__ __forceinline__ uint32_t pack2(float a, float b) {
    return f2bf(a) | (f2bf(b) << 16);
}
__device__ __forceinline__ bf16x8 u4_as_bf16x8(uint4 u) {
    union { uint4 u; bf16x8 b; } v; v.u = u; return v.b;
}
// HW bf16 conversion (compiler emits v_cvt_pk_bf16_f32 for pairs)
__device__ __forceinline__ uint2 cvt4(f32x4 v) {
    union { __bf16 b[4]; uint2 u; } o;
    o.b[0] = (__bf16)v[0]; o.b[1] = (__bf16)v[1];
    o.b[2] = (__bf16)v[2]; o.b[3] = (__bf16)v[3];
    return o.u;
}
__device__ __forceinline__ bf16x8 cvt8(f32x4 lo, f32x4 hi) {
    union { __bf16 b[8]; bf16x8 v; } o;
    o.b[0] = (__bf16)lo[0]; o.b[1] = (__bf16)lo[1];
    o.b[2] = (__bf16)lo[2]; o.b[3] = (__bf16)lo[3];
    o.b[4] = (__bf16)hi[0]; o.b[5] = (__bf16)hi[1];
    o.b[6] = (__bf16)hi[2]; o.b[7] = (__bf16)hi[3];
    return o.v;
}

// ============================================================================
// convert_zero: blocks 0..31 convert W1,W2 [128][256] fp32 -> bf16 (same
// layout, 0.1 mean-scale folded into k>=128 columns). Blocks 32..191 zero
// the used-node flags + compaction counter for this iteration.
// ============================================================================
__global__ void convert_zero(const float* __restrict__ W1, const float* __restrict__ W2,
                             uint16_t* __restrict__ O1, uint16_t* __restrict__ O2,
                             int* __restrict__ flags, int* __restrict__ counter, int N1)
{
    const int b = blockIdx.x;
    if (b < 32) {
        const float* W = (b < 16) ? W1 : W2;
        uint16_t*    O = (b < 16) ? O1 : O2;
        int t = (b & 15) * 256 + threadIdx.x;        // 0..4095, 8 elems each
        const float s = (t & 16) ? 0.1f : 1.0f;      // col block (t&31)*8 -> agg iff t&16
        const float* src = W + (size_t)t * 8;
        f32x4 a = *(const f32x4*)src * s;
        f32x4 c = *(const f32x4*)(src + 4) * s;
        uint2 lo = cvt4(a), hi = cvt4(c);
        uint4 o; o.x = lo.x; o.y = lo.y; o.z = hi.x; o.w = hi.y;
        *(uint4*)(O + (size_t)t * 8) = o;
    } else {
        if (b == 32 && threadIdx.x == 0) *counter = 0;
        for (int i = (b - 32) * 256 + threadIdx.x; i < N1; i += 160 * 256)
            flags[i] = 0;
    }
}

// ============================================================================
// mark_used: flag every layer-1 node that layer 2 will actually read
// (self rows via map_batch, neighbor rows via neigh1). Same-value races OK.
// ============================================================================
__global__ void mark_used(const int* __restrict__ map_batch,
                          const int* __restrict__ neigh1,
                          int* __restrict__ flags, int B)
{
    const int t = blockIdx.x * 256 + threadIdx.x;
    const int T = B + B * K_NEI;
    if (t >= T) return;
    const int idx = (t < B) ? map_batch[t] : neigh1[t - B];
    flags[idx] = 1;
}

// ============================================================================
// compact_used: unordered compaction of flagged node ids (order irrelevant:
// L1 output is scattered by original id). Compiler coalesces the atomics
// per-wave (ballot + one global_atomic_add).
// ============================================================================
__global__ void compact_used(const int* __restrict__ flags,
                             int* __restrict__ list, int* __restrict__ counter, int N1)
{
    const int i = blockIdx.x * 256 + threadIdx.x;
    if (i < N1 && flags[i]) {
        int p = atomicAdd(counter, 1);
        list[p] = i;
    }
}

// ============================================================================
// sage_fused: out[g] = relu([src[self[g]] | sum_k src[neigh[g][k]]] @ Wc^T)
// (0.1 mean scale pre-folded into Wc's k>=128 columns.)
//
// 128-thread blocks = 2 INDEPENDENT waves (no LDS, no barriers) -> 2x the
// schedulable blocks of R3 (occupancy was the R3 regression: 30% vs R2's 62%).
// Each wave: 16 nodes, lane (r16, q) gathers exactly its MFMA B-fragment
// (k-slices ks*32 + q*8; 4 q-lanes of one node cover each 128B line fully).
// Neighbor loads issued in PAIRS into explicit temporaries (>=16 loads in
// flight before any accumulate wait). MFMA swapped-operand (proven R2/R3):
// lane stores 4 consecutive out-cols of its own node row.
// USE_LIST: process only nodes layer-2 reads (list/cnt from compaction).
// ============================================================================
template <bool SRC_F32, bool OUT_F32, bool USE_LIST>
__global__ __launch_bounds__(128)
void sage_fused(const void* __restrict__ src_,
                const uint16_t* __restrict__ Wc,   // [128][256] bf16, agg half pre-scaled
                const int* __restrict__ self_idx,
                const int* __restrict__ neigh_idx,
                void* __restrict__ out_, int M,
                const int* __restrict__ list,
                const int* __restrict__ cnt_p)
{
    const int tid  = threadIdx.x;
    const int lane = tid & 63;
    const int r16  = lane & 15;
    const int q    = lane >> 4;
    const int base = blockIdx.x * 32 + (tid >> 6) * 16;

    int g;
    if (USE_LIST) {
        const int cnt = *cnt_p;
        if (base >= cnt) return;                 // whole-wave early exit
        int li = base + r16;
        if (li >= cnt) li = cnt - 1;             // boundary dup: same-value writes
        g = list[li];
    } else {
        g = base + r16;
        if (base >= M) return;
        if (g >= M) g = M - 1;                   // boundary dup: same-value writes
    }

    // 10 neighbor indices via 5 x int2 (rows are 40B, 8B aligned)
    const int2* nrow2 = (const int2*)(neigh_idx + (size_t)g * K_NEI);
    int idx[K_NEI];
    #pragma unroll
    for (int k = 0; k < 5; ++k) {
        int2 p = nrow2[k];
        idx[2 * k] = p.x; idx[2 * k + 1] = p.y;
    }
    const int self = self_idx[g];

    bf16x8 a[8];
    f32x4 agg[8];
    #pragma unroll
    for (int x = 0; x < 8; ++x) agg[x] = (f32x4){0.f, 0.f, 0.f, 0.f};

    if (SRC_F32) {
        const float* src  = (const float*)src_;
        const float* srow = src + (size_t)self * D + q * 8;
        f32x4 sl[8];
        #pragma unroll
        for (int ks = 0; ks < 4; ++ks) {         // self: issued early, used late
            sl[2 * ks]     = *(const f32x4*)(srow + ks * 32);
            sl[2 * ks + 1] = *(const f32x4*)(srow + ks * 32 + 4);
        }
        #pragma unroll
        for (int kp = 0; kp < 5; ++kp) {         // neighbors in pairs: 16 loads in flight
            const float* r0 = src + (size_t)idx[2 * kp]     * D + q * 8;
            const float* r1 = src + (size_t)idx[2 * kp + 1] * D + q * 8;
            f32x4 t[8], u[8];
            #pragma unroll
            for (int ks = 0; ks < 4; ++ks) {
                t[2 * ks]     = *(const f32x4*)(r0 + ks * 32);
                t[2 * ks + 1] = *(const f32x4*)(r0 + ks * 32 + 4);
                u[2 * ks]     = *(const f32x4*)(r1 + ks * 32);
                u[2 * ks + 1] = *(const f32x4*)(r1 + ks * 32 + 4);
            }
            #pragma unroll
            for (int x = 0; x < 8; ++x) agg[x] += t[x] + u[x];
        }
        #pragma unroll
        for (int ks = 0; ks < 4; ++ks)
            a[ks] = cvt8(sl[2 * ks], sl[2 * ks + 1]);
    } else {
        const uint16_t* src = (const uint16_t*)src_;
        const uint16_t* srow = src + (size_t)self * D + q * 8;
        uint4 sv[4];
        #pragma unroll
        for (int ks = 0; ks < 4; ++ks) sv[ks] = *(const uint4*)(srow + ks * 32);
        #pragma unroll
        for (int kp = 0; kp < 5; ++kp) {
            const uint16_t* r0 = src + (size_t)idx[2 * kp]     * D + q * 8;
            const uint16_t* r1 = src + (size_t)idx[2 * kp + 1] * D + q * 8;
            uint4 t[4], u[4];
            #pragma unroll
            for (int ks = 0; ks < 4; ++ks) {
                t[ks] = *(const uint4*)(r0 + ks * 32);
                u[ks] = *(const uint4*)(r1 + ks * 32);
            }
            #pragma unroll
            for (int ks = 0; ks < 4; ++ks) {
                agg[2 * ks]     += (f32x4){bf2f(t[ks].x & 0xFFFFu), bf2f(t[ks].x >> 16),
                                           bf2f(t[ks].y & 0xFFFFu), bf2f(t[ks].y >> 16)};
                agg[2 * ks + 1] += (f32x4){bf2f(t[ks].z & 0xFFFFu), bf2f(t[ks].z >> 16),
                                           bf2f(t[ks].w & 0xFFFFu), bf2f(t[ks].w >> 16)};
                agg[2 * ks]     += (f32x4){bf2f(u[ks].x & 0xFFFFu), bf2f(u[ks].x >> 16),
                                           bf2f(u[ks].y & 0xFFFFu), bf2f(u[ks].y >> 16)};
                agg[2 * ks + 1] += (f32x4){bf2f(u[ks].z & 0xFFFFu), bf2f(u[ks].z >> 16),
                                           bf2f(u[ks].w & 0xFFFFu), bf2f(u[ks].w >> 16)};
            }
        }
        #pragma unroll
        for (int ks = 0; ks < 4; ++ks) a[ks] = u4_as_bf16x8(sv[ks]);
    }
    #pragma unroll
    for (int ks = 0; ks < 4; ++ks)
        a[4 + ks] = cvt8(agg[2 * ks], agg[2 * ks + 1]);   // 0.1 folded into Wc

    f32x4 acc[8];
    #pragma unroll
    for (int nt = 0; nt < 8; ++nt) acc[nt] = (f32x4){0.f, 0.f, 0.f, 0.f};

    const uint16_t* wb = Wc + (size_t)r16 * 256 + q * 8;  // L2-hot 64KB, no reuse to exploit
    #pragma unroll
    for (int nt = 0; nt < 8; ++nt)
        #pragma unroll
        for (int ks = 0; ks < 8; ++ks) {
            bf16x8 w = *(const bf16x8*)(wb + (size_t)nt * 16 * 256 + ks * 32);
            acc[nt] = __builtin_amdgcn_mfma_f32_16x16x32_bf16(w, a[ks], acc[nt], 0, 0, 0);
        }

    // lane stores node g, out-cols nt*16 + q*4 .. +3
    #pragma unroll
    for (int nt = 0; nt < 8; ++nt) {
        f32x4 v = acc[nt];
        v[0] = v[0] > 0.f ? v[0] : 0.f;
        v[1] = v[1] > 0.f ? v[1] : 0.f;
        v[2] = v[2] > 0.f ? v[2] : 0.f;
        v[3] = v[3] > 0.f ? v[3] : 0.f;
        const int col = nt * 16 + q * 4;
        if (OUT_F32)
            *(f32x4*)((float*)out_ + (size_t)g * D + col) = v;
        else
            *(uint2*)((uint16_t*)out_ + (size_t)g * D + col) = cvt4(v);
    }
}

// ============================================================================
// Fallback: R3 fused kernel (proven) — only if ws too small / shapes off.
// ============================================================================
template <bool FEATS_F32, bool OUT_F32>
__global__ void sage_layer(const void* __restrict__ feats_,
                           const float* __restrict__ W,
                           const int* __restrict__ self_idx,
                           const int* __restrict__ neigh_idx,
                           void* __restrict__ out_)
{
    __shared__ __align__(16) uint16_t Alds[TILE_M * 128];
    __shared__ __align__(16) uint16_t Wlds[128 * 128];

    const int tid  = threadIdx.x;
    const int wave = tid >> 6;
    const int lane = tid & 63;
    const int r16  = lane & 15;
    const int q    = lane >> 4;
    const int G    = blockIdx.x * TILE_M;

    const float*    feats_f = (const float*)feats_;
    const uint16_t* feats_b = (const uint16_t*)feats_;

    f32x4 acc[8];
    #pragma unroll
    for (int nt = 0; nt < 8; ++nt) acc[nt] = (f32x4){0.f, 0.f, 0.f, 0.f};

    for (int half = 0; half < 2; ++half) {
        #pragma unroll
        for (int it = 0; it < 8; ++it) {
            int t = it * 256 + tid;
            int j = t >> 4, c = t & 15;
            const float* src = W + (size_t)j * 256 + half * 128 + c * 8;
            f32x4 w0 = *(const f32x4*)(src);
            f32x4 w1 = *(const f32x4*)(src + 4);
            uint4 o;
            o.x = pack2(w0[0], w0[1]); o.y = pack2(w0[2], w0[3]);
            o.z = pack2(w1[0], w1[1]); o.w = pack2(w1[2], w1[3]);
            int cs = c ^ (j & 15);
            *(uint4*)(Wlds + j * 128 + cs * 8) = o;
        }
        if (half == 0) {
            #pragma unroll
            for (int it = 0; it < 4; ++it) {
                int t = it * 256 + tid;
                int n = t >> 4, c = t & 15;
                int node = self_idx[G + n];
                uint4 o;
                if (FEATS_F32) {
                    const float* src = feats_f + (size_t)node * D + c * 8;
                    f32x4 f0 = *(const f32x4*)(src);
                    f32x4 f1 = *(const f32x4*)(src + 4);
                    o.x = pack2(f0[0], f0[1]); o.y = pack2(f0[2], f0[3]);
                    o.z = pack2(f1[0], f1[1]); o.w = pack2(f1[2], f1[3]);
                } else {
                    o = *(const uint4*)(feats_b + (size_t)node * D + c * 8);
                }
                int cs = c ^ (n & 15);
                *(uint4*)(Alds + n * 128 + cs * 8) = o;
            }
        } else {
            #pragma unroll
            for (int it = 0; it < 4; ++it) {
                int t = it * 256 + tid;
                int n = t >> 4, c = t & 15;
                const int* nrow = neigh_idx + (size_t)(G + n) * K_NEI;
                float s0=0,s1=0,s2=0,s3=0,s4=0,s5=0,s6=0,s7=0;
                #pragma unroll
                for (int k = 0; k < K_NEI; ++k) {
                    if (FEATS_F32) {
                        const float* src = feats_f + (size_t)nrow[k] * D + c * 8;
                        f32x4 f0 = *(const f32x4*)(src);
                        f32x4 f1 = *(const f32x4*)(src + 4);
                        s0 += f0[0]; s1 += f0[1]; s2 += f0[2]; s3 += f0[3];
                        s4 += f1[0]; s5 += f1[1]; s6 += f1[2]; s7 += f1[3];
                    } else {
                        uint4 v = *(const uint4*)(feats_b + (size_t)nrow[k] * D + c * 8);
                        s0 += bf2f(v.x & 0xFFFFu); s1 += bf2f(v.x >> 16);
                        s2 += bf2f(v.y & 0xFFFFu); s3 += bf2f(v.y >> 16);
                        s4 += bf2f(v.z & 0xFFFFu); s5 += bf2f(v.z >> 16);
                        s6 += bf2f(v.w & 0xFFFFu); s7 += bf2f(v.w >> 16);
                    }
                }
                const float inv = 0.1f;
                uint4 o;
                o.x = pack2(s0 * inv, s1 * inv);
                o.y = pack2(s2 * inv, s3 * inv);
                o.z = pack2(s4 * inv, s5 * inv);
                o.w = pack2(s6 * inv, s7 * inv);
                int cs = c ^ (n & 15);
                *(uint4*)(Alds + n * 128 + cs * 8) = o;
            }
        }
        __syncthreads();

        #pragma unroll
        for (int ks = 0; ks < 4; ++ks) {
            int cidx = ks * 4 + q;
            bf16x8 a = *(const bf16x8*)(Alds + (wave * 16 + r16) * 128 + ((cidx ^ r16) * 8));
            bf16x8 b[8];
            #pragma unroll
            for (int nt = 0; nt < 8; ++nt) {
                int jj = nt * 16 + r16;
                b[nt] = *(const bf16x8*)(Wlds + jj * 128 + ((cidx ^ r16) * 8));
            }
            #pragma unroll
            for (int nt = 0; nt < 8; ++nt)
                acc[nt] = __builtin_amdgcn_mfma_f32_16x16x32_bf16(a, b[nt], acc[nt], 0, 0, 0);
        }
        __syncthreads();
    }

    const int row_base = G + wave * 16 + q * 4;
    #pragma unroll
    for (int nt = 0; nt < 8; ++nt) {
        int col = nt * 16 + r16;
        #pragma unroll
        for (int r = 0; r < 4; ++r) {
            float v = acc[nt][r];
            v = v > 0.f ? v : 0.f;
            if (OUT_F32) ((float*)out_)[(size_t)(row_base + r) * D + col] = v;
            else ((uint16_t*)out_)[(size_t)(row_base + r) * D + col] = (uint16_t)f2bf(v);
        }
    }
}

extern "C" void kernel_launch(void* const* d_in, const int* in_sizes, int n_in,
                              void* d_out, int out_size, void* d_ws, size_t ws_size,
                              hipStream_t stream) {
    const float* raw = (const float*)d_in[0];          // [200000][128] fp32
    const float* W1  = (const float*)d_in[1];          // [128][256] fp32
    const float* W2  = (const float*)d_in[2];          // [128][256] fp32
    const int* layer1_nodes = (const int*)d_in[3];     // [81920]
    const int* neigh0       = (const int*)d_in[4];     // [81920][10]
    const int* map_batch    = (const int*)d_in[5];     // [8192]
    const int* neigh1       = (const int*)d_in[6];     // [8192][10]

    const int N1 = in_sizes[3];            // 81920
    const int B  = in_sizes[5];            // 8192

    const size_t szH1 = (size_t)N1 * 128 * 2;          // 21.0 MB
    const size_t szW  = 128 * 256 * 2;                 // 64 KB
    const size_t szAux = (size_t)N1 * 4 * 2 + 64;      // flags + list + counter
    const size_t need = szH1 + 2 * szW + szAux;

    if (ws_size >= need && (N1 % 16) == 0 && (B % 16) == 0) {
        uint16_t* h1   = (uint16_t*)d_ws;
        uint16_t* W1c  = h1 + (size_t)N1 * 128;
        uint16_t* W2c  = W1c + 128 * 256;
        int*      flags   = (int*)(W2c + 128 * 256);
        int*      list    = flags + N1;
        int*      counter = list + N1;

        // Convert weights + zero flags/counter (one launch, independent halves).
        convert_zero<<<192, 256, 0, stream>>>(W1, W2, W1c, W2c, flags, counter, N1);

        // Flag + compact the ~67% of layer-1 nodes layer 2 actually reads.
        mark_used<<<(B + B * K_NEI + 255) / 256, 256, 0, stream>>>(map_batch, neigh1, flags, B);
        compact_used<<<(N1 + 255) / 256, 256, 0, stream>>>(flags, list, counter, N1);

        // Layer 1: gather + mean + GEMM fused, only over used nodes.
        sage_fused<true,  false, true ><<<(N1 + 31) / 32, 128, 0, stream>>>(
            raw, W1c, layer1_nodes, neigh0, h1, N1, list, counter);

        // Layer 2: all batch rows, fp32 output.
        sage_fused<false, true,  false><<<(B + 31) / 32, 128, 0, stream>>>(
            h1, W2c, map_batch, neigh1, d_out, B, nullptr, nullptr);
        return;
    }

    // Fallback: R3 fused path
    uint16_t* h1 = (uint16_t*)d_ws;
    sage_layer<true,  false><<<N1 / TILE_M, 256, 0, stream>>>(raw, W1, layer1_nodes, neigh0, h1);
    sage_layer<false, true ><<<B  / TILE_M, 256, 0, stream>>>(h1,  W2, map_batch,    neigh1, d_out);
}